// Round 1
// baseline (396.539 us; speedup 1.0000x reference)
//
#include <hip/hip_runtime.h>
#include <hip/hip_bf16.h>

// Problem constants: B=4, C=384, H=W=56 (S=3136), NH=12, HD=32, WS=7, pad=3.
#define S_HW 3136
#define IMG_W 56
#define C_DIM 384
#define NH_DIM 12
#define HD_DIM 32

// ---------------------------------------------------------------------------
// Generic fp32 GEMM with bias: Y[b][o][s] = sum_c W[o][c] * X[b][c][s] + bias[o]
// Rows o < qrows get multiplied by qscale (for the q part of qkv).
// Tile 128x128, BK=8, 256 threads, 8x8 per thread.
// Requires O % 128 == 0, K % 8 == 0. S guarded.
// ---------------------------------------------------------------------------
__global__ __launch_bounds__(256) void gemm_bias_kernel(
    const float* __restrict__ Wm, const float* __restrict__ X,
    const float* __restrict__ bias, float* __restrict__ Y,
    int O, int K, int S, float qscale, int qrows)
{
    constexpr int BM = 128, BN = 128, BK = 8;
    __shared__ float As[BK][BM];   // transposed: As[k][m]
    __shared__ float Bs[BK][BN];

    const int b  = blockIdx.z;
    const int m0 = blockIdx.y * BM;
    const int n0 = blockIdx.x * BN;
    const float* Xb = X + (size_t)b * K * S;
    float* Yb = Y + (size_t)b * O * S;

    const int tid = threadIdx.x;
    const int tx = tid % 16;       // n direction (interleaved cols)
    const int ty = tid / 16;       // m direction (blocked rows)

    // A-tile load mapping: thread -> W[m0 + tid/2][k0 + (tid%2)*4 .. +3]
    const int arow  = tid >> 1;          // 0..127
    const int acol4 = (tid & 1) * 4;     // 0 or 4
    // B-tile load mapping: thread -> X[k0 + tid/32][n0 + (tid%32)*4 .. +3]
    const int brow  = tid >> 5;          // 0..7
    const int bcol4 = (tid & 31) * 4;    // 0..124

    float acc[8][8];
    #pragma unroll
    for (int i = 0; i < 8; ++i)
        #pragma unroll
        for (int j = 0; j < 8; ++j) acc[i][j] = 0.f;

    for (int k0 = 0; k0 < K; k0 += BK) {
        // ---- stage A (always in range: O multiple of 128, K multiple of 8)
        float4 av = *reinterpret_cast<const float4*>(
            &Wm[(size_t)(m0 + arow) * K + k0 + acol4]);
        As[acol4 + 0][arow] = av.x;
        As[acol4 + 1][arow] = av.y;
        As[acol4 + 2][arow] = av.z;
        As[acol4 + 3][arow] = av.w;
        // ---- stage B (column-guarded; S % 4 == 0 so float4 is all-or-nothing)
        const int bc = n0 + bcol4;
        if (bc < S) {
            float4 bv = *reinterpret_cast<const float4*>(
                &Xb[(size_t)(k0 + brow) * S + bc]);
            *reinterpret_cast<float4*>(&Bs[brow][bcol4]) = bv;
        }
        __syncthreads();

        #pragma unroll
        for (int kk = 0; kk < BK; ++kk) {
            float a[8], bb[8];
            float4 a0 = *reinterpret_cast<const float4*>(&As[kk][ty * 8]);
            float4 a1 = *reinterpret_cast<const float4*>(&As[kk][ty * 8 + 4]);
            a[0] = a0.x; a[1] = a0.y; a[2] = a0.z; a[3] = a0.w;
            a[4] = a1.x; a[5] = a1.y; a[6] = a1.z; a[7] = a1.w;
            #pragma unroll
            for (int j = 0; j < 8; ++j) bb[j] = Bs[kk][tx + j * 16];
            #pragma unroll
            for (int i = 0; i < 8; ++i)
                #pragma unroll
                for (int j = 0; j < 8; ++j)
                    acc[i][j] = fmaf(a[i], bb[j], acc[i][j]);
        }
        __syncthreads();
    }

    #pragma unroll
    for (int i = 0; i < 8; ++i) {
        const int row = m0 + ty * 8 + i;
        const float bi = bias[row];
        const float sc = (row < qrows) ? qscale : 1.f;
        #pragma unroll
        for (int j = 0; j < 8; ++j) {
            const int col = n0 + tx + j * 16;
            if (col < S) Yb[(size_t)row * S + col] = (acc[i][j] + bi) * sc;
        }
    }
}

// ---------------------------------------------------------------------------
// Neighborhood attention: one thread per pixel per head.
// qkv layout: [b][1152][S]; q rows 0..383 (pre-scaled), k rows 384..767,
// v rows 768..1151. out layout: [b][384][S] with channel = nh*32 + hd.
// ---------------------------------------------------------------------------
__global__ __launch_bounds__(256) void na_attn_kernel(
    const float* __restrict__ qkv, const float* __restrict__ rel_bias,
    float* __restrict__ out)
{
    const int blk  = blockIdx.x;          // b*NH*13 + nh*13 + tile
    const int tile = blk % 13;
    const int bn   = blk / 13;
    const int nh   = bn % NH_DIM;
    const int b    = bn / NH_DIM;
    const int s    = tile * 256 + threadIdx.x;
    if (s >= S_HW) return;
    const int h = s / IMG_W;
    const int w = s % IMG_W;

    const float* qb = qkv + ((size_t)b * 1152 + nh * HD_DIM) * S_HW;
    const float* kb = qb + (size_t)C_DIM * S_HW;
    const float* vb = qb + (size_t)(2 * C_DIM) * S_HW;

    float q[32];
    #pragma unroll
    for (int c = 0; c < 32; ++c) q[c] = qb[(size_t)c * S_HW + s];

    float logits[49];
    #pragma unroll
    for (int di = 0; di < 7; ++di) {
        int y = h + di - 3; y = min(max(y, 0), 55);
        #pragma unroll
        for (int dj = 0; dj < 7; ++dj) {
            int x = w + dj - 3; x = min(max(x, 0), 55);
            const int ks = y * IMG_W + x;
            float dot = 0.f;
            #pragma unroll
            for (int c = 0; c < 32; ++c)
                dot = fmaf(q[c], kb[(size_t)c * S_HW + ks], dot);
            logits[di * 7 + dj] = dot + rel_bias[(nh * 7 + di) * 7 + dj];
        }
    }

    float mx = logits[0];
    #pragma unroll
    for (int i = 1; i < 49; ++i) mx = fmaxf(mx, logits[i]);
    float sum = 0.f;
    #pragma unroll
    for (int i = 0; i < 49; ++i) { logits[i] = __expf(logits[i] - mx); sum += logits[i]; }
    const float inv = 1.f / sum;

    float o[32];
    #pragma unroll
    for (int c = 0; c < 32; ++c) o[c] = 0.f;
    #pragma unroll
    for (int di = 0; di < 7; ++di) {
        int y = h + di - 3; y = min(max(y, 0), 55);
        #pragma unroll
        for (int dj = 0; dj < 7; ++dj) {
            int x = w + dj - 3; x = min(max(x, 0), 55);
            const int ks = y * IMG_W + x;
            const float p = logits[di * 7 + dj];
            #pragma unroll
            for (int c = 0; c < 32; ++c)
                o[c] = fmaf(p, vb[(size_t)c * S_HW + ks], o[c]);
        }
    }

    float* ob = out + ((size_t)b * C_DIM + nh * HD_DIM) * S_HW;
    #pragma unroll
    for (int c = 0; c < 32; ++c) ob[(size_t)c * S_HW + s] = o[c] * inv;
}

// ---------------------------------------------------------------------------
extern "C" void kernel_launch(void* const* d_in, const int* in_sizes, int n_in,
                              void* d_out, int out_size, void* d_ws, size_t ws_size,
                              hipStream_t stream) {
    const float* x        = (const float*)d_in[0];
    const float* w_qkv    = (const float*)d_in[1];
    const float* b_qkv    = (const float*)d_in[2];
    const float* w_proj   = (const float*)d_in[3];
    const float* b_proj   = (const float*)d_in[4];
    const float* rel_bias = (const float*)d_in[5];
    float* out = (float*)d_out;

    // Workspace: qkv [4][1152][3136] fp32 (57.8 MB) + attn [4][384][3136] (19.3 MB)
    float* qkv  = (float*)d_ws;
    float* attn = qkv + (size_t)4 * 1152 * S_HW;

    const float scale = 0.17677669529663687f;  // 32^-0.5

    // qkv projection: O=1152, K=384 over S=3136, 4 batches
    dim3 g1((S_HW + 127) / 128, 1152 / 128, 4);
    gemm_bias_kernel<<<g1, 256, 0, stream>>>(w_qkv, x, b_qkv, qkv,
                                             1152, C_DIM, S_HW, scale, C_DIM);

    // attention: 4*12 head-slabs x 13 pixel tiles of 256
    na_attn_kernel<<<dim3(4 * NH_DIM * 13), 256, 0, stream>>>(qkv, rel_bias, attn);

    // output projection: O=384, K=384
    dim3 g3((S_HW + 127) / 128, C_DIM / 128, 4);
    gemm_bias_kernel<<<g3, 256, 0, stream>>>(w_proj, attn, b_proj, out,
                                             C_DIM, C_DIM, S_HW, 1.f, 0);
}